// Round 7
// baseline (12233.911 us; speedup 1.0000x reference)
//
#include <hip/hip_runtime.h>
#include <stdint.h>

typedef short short8 __attribute__((ext_vector_type(8)));
typedef float floatx4 __attribute__((ext_vector_type(4)));
typedef unsigned long long u64;

__device__ __forceinline__ unsigned short f2bf(float f) {
  union { float f; unsigned int i; } v;
  v.f = f;
  unsigned int r = v.i + 0x7fffu + ((v.i >> 16) & 1u);
  return (unsigned short)(r >> 16);
}
// convert 8 consecutive floats (two float4) -> short8 of bf16 bits
__device__ __forceinline__ short8 cvt8(const float4 a, const float4 b) {
  short8 v;
  v[0] = (short)f2bf(a.x); v[1] = (short)f2bf(a.y);
  v[2] = (short)f2bf(a.z); v[3] = (short)f2bf(a.w);
  v[4] = (short)f2bf(b.x); v[5] = (short)f2bf(b.y);
  v[6] = (short)f2bf(b.z); v[7] = (short)f2bf(b.w);
  return v;
}
// NaN-killing clamp: fmaxf(NaN, lo) == lo (v_max_f32, IEEE mode).
__device__ __forceinline__ float sane(float x, float lim) {
  return fminf(fmaxf(x, -lim), lim);
}

extern __shared__ unsigned short lds[];

// ---------------------------------------------------------------------------
// Fused persistent BiGRU layer (FLOAT32 I/O, bf16 MFMA compute).
// 64 blocks x 128 threads: blocks 0..31 forward, 32..63 backward.
// Block d owns 16 hidden cols. LDS: whs[48][520] + wxs[48][K+8] bf16.
// Weights (float [1536][K] / [1536][512]) are converted to bf16 at staging.
// Per step: gx(t) precomputed in the previous step's spin window; gh = h_prev
// @ wh^T via MFMA reading the exchange buffer with agent-scope atomics;
// gates in fp32; h carried in fp32 registers.
// exmode=0 (layer0): exch = y0 [512][32][1024] bf16 (exchange + next input).
// exmode=1 (layer1): exch = ring [2][32][1024] bf16; omain = float
//   [32][512][1024] final output.
// xmode=1: xf = x float [B][S][512], K=512.
// xmode=0: xb = y0 bf16 [S][B][1024], K=1024.
// ---------------------------------------------------------------------------
__global__ __launch_bounds__(128)
void gru_layer(const float* __restrict__ xf,
               const unsigned short* __restrict__ xb,
               const float* __restrict__ wxfp,
               const float* __restrict__ bxfp,
               const float* __restrict__ whfp,
               const float* __restrict__ bhfp,
               const float* __restrict__ wxbp,
               const float* __restrict__ bxbp,
               const float* __restrict__ whbp,
               const float* __restrict__ bhbp,
               unsigned short* __restrict__ exch,
               float* __restrict__ omain,
               float* __restrict__ out_hf,   // float [32][512]
               float* __restrict__ out_hb,   // float [32][512]
               int* __restrict__ flags,      // 64 ints, zeroed
               const int K, const int xmode, const int exmode)
{
  unsigned short* whs = lds;               // [48][520] bf16
  unsigned short* wxs = lds + 48 * 520;    // [48][K+8] bf16
  const int WXW = K + 8;
  const int KC = K >> 3;                   // 8-float chunks per wx row
  const int ksh = (K == 512) ? 6 : 7;

  const int bid = blockIdx.x;
  const bool fw = bid < 32;
  const int d = fw ? bid : bid - 32;
  const int tid = threadIdx.x;
  const int lane = tid & 63;
  const int w = tid >> 6;
  const int q = lane >> 4;
  const int l16 = lane & 15;

  const float* wx = fw ? wxfp : wxbp;
  const float* bx = fw ? bxfp : bxbp;
  const float* wh = fw ? whfp : whbp;
  const float* bh = fw ? bhfp : bhbp;
  const int col0 = d * 16;
  const int dirofs = fw ? 0 : 512;

  unsigned int* exch32 = (unsigned int*)exch;

  // stage wh rows (g*512 + col0 + jc) of float [1536][512] -> bf16 whs
  for (int c = tid; c < 48 * 64; c += 128) {
    int lr = c >> 6, c8 = (c & 63) * 8;
    int g = lr >> 4, jc = lr & 15;
    const float* src = wh + (long)(g * 512 + col0 + jc) * 512 + c8;
    *(short8*)(whs + lr * 520 + c8) =
        cvt8(*(const float4*)src, *(const float4*)(src + 4));
  }
  // stage wx rows (g*512 + col0 + jc) of float [1536][K] -> bf16 wxs
  for (int c = tid; c < 48 * KC; c += 128) {
    int lr = c >> ksh, c8 = (c & (KC - 1)) * 8;
    int g = lr >> 4, jc = lr & 15;
    const float* src = wx + (long)(g * 512 + col0 + jc) * K + c8;
    *(short8*)(wxs + lr * WXW + c8) =
        cvt8(*(const float4*)src, *(const float4*)(src + 4));
  }
  __syncthreads();

  const int jj = l16;                      // this lane's local hidden col
  const int gcr = col0 + jj;
  const int gcz = 512 + col0 + jj;
  const int gcn = 1024 + col0 + jj;
  const float cr = bx[gcr] + bh[gcr];      // r-gate bias constant
  const float cz = bx[gcz] + bh[gcz];      // z-gate bias constant
  const float bxn = bx[gcn];
  const float bhn = bh[gcn];

  const int cb = w * 16 + q * 4;           // C-layout batch base
  const int ab = w * 16 + l16;             // A-layout batch row
  const int peer = (fw ? 0 : 32) + (tid & 31);

  const floatx4 fz = {0.f, 0.f, 0.f, 0.f};
  float h[4] = {0.f, 0.f, 0.f, 0.f};

  // gx(t) = bf16(x_t) @ bf16(wx)^T for this block's 48 gate-cols (C-layout).
  auto compute_gx = [&](int t, floatx4& gr, floatx4& gz, floatx4& gn) {
    gr = fz; gz = fz; gn = fz;
    const int nks = K >> 5;
    for (int ks = 0; ks < nks; ++ks) {
      short8 a;
      if (xmode) {
        const float* p = xf + ((long)ab * 512 + t) * 512 + ks * 32 + q * 8;
        a = cvt8(*(const float4*)p, *(const float4*)(p + 4));
      } else {
        a = *(const short8*)(xb + ((long)t * 32 + ab) * 1024 + ks * 32 + q * 8);
      }
      short8 vr = *(const short8*)(wxs + (jj) * WXW + ks * 32 + q * 8);
      short8 vz = *(const short8*)(wxs + (16 + jj) * WXW + ks * 32 + q * 8);
      short8 vn = *(const short8*)(wxs + (32 + jj) * WXW + ks * 32 + q * 8);
      gr = __builtin_amdgcn_mfma_f32_16x16x32_bf16(a, vr, gr, 0, 0, 0);
      gz = __builtin_amdgcn_mfma_f32_16x16x32_bf16(a, vz, gz, 0, 0, 0);
      gn = __builtin_amdgcn_mfma_f32_16x16x32_bf16(a, vn, gn, 0, 0, 0);
    }
  };

  floatx4 gxr, gxz, gxn, nxr, nxz, nxn;
  { const int t0 = fw ? 0 : 511; compute_gx(t0, gxr, gxz, gxn); }

  for (int it = 0; it < 512; ++it) {
    const int t = fw ? it : 511 - it;

    floatx4 ar = fz, az = fz, an = fz;
    if (it > 0) {
      const unsigned short* hbase;
      if (exmode == 0) {
        const int tprev = fw ? t - 1 : t + 1;
        hbase = exch + ((long)tprev * 32 + ab) * 1024 + dirofs;
      } else {
        const int slot_r = (it + 1) & 1;           // slot written at it-1
        hbase = exch + ((long)slot_r * 32 + ab) * 1024 + dirofs;
      }
      short8 af[16];
#pragma unroll
      for (int ks = 0; ks < 16; ++ks) {
        u64* p = (u64*)(hbase + ks * 32 + q * 8);
        union { u64 u[2]; short8 s; } t8;
        t8.u[0] = __hip_atomic_load(p,     __ATOMIC_RELAXED, __HIP_MEMORY_SCOPE_AGENT);
        t8.u[1] = __hip_atomic_load(p + 1, __ATOMIC_RELAXED, __HIP_MEMORY_SCOPE_AGENT);
        af[ks] = t8.s;
      }
#pragma unroll
      for (int ks = 0; ks < 16; ++ks) {
        short8 vr = *(const short8*)(whs + (jj) * 520 + ks * 32 + q * 8);
        short8 vz = *(const short8*)(whs + (16 + jj) * 520 + ks * 32 + q * 8);
        short8 vn = *(const short8*)(whs + (32 + jj) * 520 + ks * 32 + q * 8);
        ar = __builtin_amdgcn_mfma_f32_16x16x32_bf16(af[ks], vr, ar, 0, 0, 0);
        az = __builtin_amdgcn_mfma_f32_16x16x32_bf16(af[ks], vz, az, 0, 0, 0);
        an = __builtin_amdgcn_mfma_f32_16x16x32_bf16(af[ks], vn, an, 0, 0, 0);
      }
    }

    unsigned short hb16[4];
#pragma unroll
    for (int r = 0; r < 4; ++r) {
      const float xr = sane(gxr[r] + ar[r] + cr, 60.f);
      const float xz = sane(gxz[r] + az[r] + cz, 60.f);
      const float rr = 1.f / (1.f + __expf(-xr));
      const float zz = 1.f / (1.f + __expf(-xz));
      const float xn = sane(gxn[r] + bxn + rr * (an[r] + bhn), 30.f);
      const float e2 = __expf(-2.f * xn);
      const float nn = (1.f - e2) / (1.f + e2);
      h[r] = (1.f - zz) * nn + zz * h[r];
      hb16[r] = f2bf(h[r]);
    }

    // exchange: pack 2 adjacent cols -> one 32-bit agent-scope atomic store
    unsigned int hw[4];
#pragma unroll
    for (int r = 0; r < 4; ++r) {
      int v = hb16[r];
      int p = __shfl_xor(v, 1);
      hw[r] = (unsigned int)(v & 0xffff) | ((unsigned int)(p & 0xffff) << 16);
    }
    if ((jj & 1) == 0) {
      const int colw = (dirofs + col0 + jj) >> 1;
#pragma unroll
      for (int r = 0; r < 4; ++r) {
        const long eidx = (exmode == 0)
            ? (((long)t * 32 + cb + r) * 512 + colw)
            : (((long)(it & 1) * 32 + cb + r) * 512 + colw);
        __hip_atomic_store(exch32 + eidx, hw[r],
                           __ATOMIC_RELAXED, __HIP_MEMORY_SCOPE_AGENT);
      }
    }
    // float32 main output (layer 1 only): [B][S][1024]
    if (exmode == 1) {
#pragma unroll
      for (int r = 0; r < 4; ++r)
        omain[(long)(cb + r) * 524288 + (long)t * 1024 + dirofs + col0 + jj] = h[r];
    }

    if (it == 511) {
      float* oh = fw ? out_hf : out_hb;
#pragma unroll
      for (int r = 0; r < 4; ++r)
        oh[(cb + r) * 512 + col0 + jj] = h[r];
    } else {
      __syncthreads();   // each wave drains vmcnt(0) before s_barrier
      if (tid == 0)
        __hip_atomic_store(&flags[bid], it + 1, __ATOMIC_RELEASE, __HIP_MEMORY_SCOPE_AGENT);
      // compute next step's gx during the spin window (peer-independent)
      {
        const int tn2 = fw ? (it + 1) : (511 - (it + 1));
        compute_gx(tn2, nxr, nxz, nxn);
      }
      // every thread acquires on a peer flag -> its own loads are ordered
      while (__hip_atomic_load(&flags[peer], __ATOMIC_ACQUIRE, __HIP_MEMORY_SCOPE_AGENT) < it + 1)
        __builtin_amdgcn_s_sleep(1);
      __syncthreads();
      gxr = nxr; gxz = nxz; gxn = nxn;
    }
  }
}

// ---------------------------------------------------------------------------
// ws layout (total 33,686,016 B ~= 32.1 MiB):
//   y0    @ 0          : 33554432   bf16 [512][32][1024] — layer0 exchange +
//                                   output, layer1 input
//   ring1 @ 33554432   : 131072     bf16 [2][32][1024] — layer1 exchange
//   flags @ 33685504   : 512        (64 ints layer0, 64 ints layer1)
// d_out (FLOAT32): main [32][512][1024] @0, h_fw [2][32][512] @16777216,
// h_bw [2][32][512] @16809984.
// ---------------------------------------------------------------------------
extern "C" void kernel_launch(void* const* d_in, const int* in_sizes, int n_in,
                              void* d_out, int out_size, void* d_ws, size_t ws_size,
                              hipStream_t stream)
{
  (void)in_sizes; (void)n_in; (void)out_size; (void)ws_size;

  const float* x    = (const float*)d_in[0];
  const float* wxf0 = (const float*)d_in[1];
  const float* bxf0 = (const float*)d_in[2];
  const float* whf0 = (const float*)d_in[3];
  const float* bhf0 = (const float*)d_in[4];
  const float* wxb0 = (const float*)d_in[5];
  const float* bxb0 = (const float*)d_in[6];
  const float* whb0 = (const float*)d_in[7];
  const float* bhb0 = (const float*)d_in[8];
  const float* wxf1 = (const float*)d_in[9];
  const float* bxf1 = (const float*)d_in[10];
  const float* whf1 = (const float*)d_in[11];
  const float* bhf1 = (const float*)d_in[12];
  const float* wxb1 = (const float*)d_in[13];
  const float* bxb1 = (const float*)d_in[14];
  const float* whb1 = (const float*)d_in[15];
  const float* bhb1 = (const float*)d_in[16];

  char* ws = (char*)d_ws;
  unsigned short* y0    = (unsigned short*)(ws);
  unsigned short* ring1 = (unsigned short*)(ws + 33554432L);
  int* flags0           = (int*)(ws + 33685504L);
  int* flags1           = flags0 + 64;

  float* out = (float*)d_out;
  float* out_hf0 = out + 16777216L;
  float* out_hf1 = out + 16777216L + 16384L;
  float* out_hb0 = out + 16777216L + 32768L;
  float* out_hb1 = out + 16777216L + 49152L;

  const size_t lds0 = (size_t)(48 * 520 + 48 * (512 + 8)) * 2;    //  99,840 B
  const size_t lds1 = (size_t)(48 * 520 + 48 * (1024 + 8)) * 2;   // 148,992 B
  (void)hipFuncSetAttribute((const void*)gru_layer,
                            hipFuncAttributeMaxDynamicSharedMemorySize,
                            (int)lds1);

  hipMemsetAsync(flags0, 0, 512, stream);

  // layer 0: x float [B][S][512] -> y0 bf16 [S][B][1024] (+ h outputs)
  gru_layer<<<dim3(64), dim3(128), lds0, stream>>>(
      x, nullptr, wxf0, bxf0, whf0, bhf0, wxb0, bxb0, whb0, bhb0,
      y0, nullptr, out_hf0, out_hb0, flags0, 512, 1, 0);

  // layer 1: y0 bf16 [S][B][1024] -> d_out main float [B][S][1024] (+ h)
  gru_layer<<<dim3(64), dim3(128), lds1, stream>>>(
      nullptr, y0, wxf1, bxf1, whf1, bhf1, wxb1, bxb1, whb1, bhb1,
      ring1, out, out_hf1, out_hb1, flags1, 1024, 0, 1);
}

// Round 8
// 7727.005 us; speedup vs baseline: 1.5833x; 1.5833x over previous
//
#include <hip/hip_runtime.h>
#include <stdint.h>

typedef short short8 __attribute__((ext_vector_type(8)));
typedef float floatx4 __attribute__((ext_vector_type(4)));
typedef unsigned long long u64;

__device__ __forceinline__ unsigned short f2bf(float f) {
  union { float f; unsigned int i; } v;
  v.f = f;
  unsigned int r = v.i + 0x7fffu + ((v.i >> 16) & 1u);
  return (unsigned short)(r >> 16);
}
__device__ __forceinline__ short8 cvt8(const float4 a, const float4 b) {
  short8 v;
  v[0] = (short)f2bf(a.x); v[1] = (short)f2bf(a.y);
  v[2] = (short)f2bf(a.z); v[3] = (short)f2bf(a.w);
  v[4] = (short)f2bf(b.x); v[5] = (short)f2bf(b.y);
  v[6] = (short)f2bf(b.z); v[7] = (short)f2bf(b.w);
  return v;
}
// NaN-killing clamp: fmaxf(NaN, lo) == lo (v_max_f32, IEEE mode).
__device__ __forceinline__ float sane(float x, float lim) {
  return fminf(fmaxf(x, -lim), lim);
}

extern __shared__ unsigned short lds[];

// ---------------------------------------------------------------------------
// Fused persistent BiGRU layer (float32 I/O, bf16 MFMA compute).
// 64 blocks x 128 threads: blocks 0..31 forward, 32..63 backward.
// Block d owns 16 hidden cols; whs[48][520] + wxs[48][K+8] bf16 in LDS.
// Step pipeline: af (h_prev) atomic loads + x(t+1) register prefetch issued
// together -> gh MFMAs -> gates (fp32) -> h stores -> barrier -> flag post ->
// gx(t+1) MFMAs (pure LDS/VALU, no memory) -> wave0 polls 32 padded flags ->
// barrier. Flags: one per 64B line; only lanes 0..31 of wave 0 poll (relaxed;
// safety = uncached atomic h data + barrier execution ordering).
// EM=0 (layer0): exch = y0 [512][32][1024] bf16 (exchange + next input).
// EM=1 (layer1): exch = ring [2][32][1024] bf16; omain = float [32][512][1024].
// XM=1: xf float [B][S][512], K=512.  XM=0: xb bf16 [S][B][1024], K=1024.
// ---------------------------------------------------------------------------
template<int K, int XM, int EM>
__global__ __launch_bounds__(128)
void gru_layer(const float* __restrict__ xf,
               const unsigned short* __restrict__ xb,
               const float* __restrict__ wxfp,
               const float* __restrict__ bxfp,
               const float* __restrict__ whfp,
               const float* __restrict__ bhfp,
               const float* __restrict__ wxbp,
               const float* __restrict__ bxbp,
               const float* __restrict__ whbp,
               const float* __restrict__ bhbp,
               unsigned short* __restrict__ exch,
               float* __restrict__ omain,
               float* __restrict__ out_hf,   // float [32][512]
               float* __restrict__ out_hb,   // float [32][512]
               int* __restrict__ flags)      // 64 x 16 ints (64B-padded)
{
  constexpr int NKS = K / 32;                // 16 (K=512) or 32 (K=1024)
  constexpr int WXW = K + 8;
  constexpr int KC = K >> 3;
  constexpr int KSH = (K == 512) ? 6 : 7;

  unsigned short* whs = lds;                 // [48][520] bf16
  unsigned short* wxs = lds + 48 * 520;      // [48][WXW] bf16

  const int bid = blockIdx.x;
  const bool fw = bid < 32;
  const int d = fw ? bid : bid - 32;
  const int tid = threadIdx.x;
  const int lane = tid & 63;
  const int w = tid >> 6;
  const int q = lane >> 4;
  const int l16 = lane & 15;

  const float* wx = fw ? wxfp : wxbp;
  const float* bx = fw ? bxfp : bxbp;
  const float* wh = fw ? whfp : whbp;
  const float* bh = fw ? bhfp : bhbp;
  const int col0 = d * 16;
  const int dirofs = fw ? 0 : 512;

  unsigned int* exch32 = (unsigned int*)exch;

  // stage wh rows (g*512 + col0 + jc) of float [1536][512] -> bf16 whs
  for (int c = tid; c < 48 * 64; c += 128) {
    int lr = c >> 6, c8 = (c & 63) * 8;
    int g = lr >> 4, jc = lr & 15;
    const float* src = wh + (long)(g * 512 + col0 + jc) * 512 + c8;
    *(short8*)(whs + lr * 520 + c8) =
        cvt8(*(const float4*)src, *(const float4*)(src + 4));
  }
  // stage wx rows (g*512 + col0 + jc) of float [1536][K] -> bf16 wxs
  for (int c = tid; c < 48 * KC; c += 128) {
    int lr = c >> KSH, c8 = (c & (KC - 1)) * 8;
    int g = lr >> 4, jc = lr & 15;
    const float* src = wx + (long)(g * 512 + col0 + jc) * K + c8;
    *(short8*)(wxs + lr * WXW + c8) =
        cvt8(*(const float4*)src, *(const float4*)(src + 4));
  }
  __syncthreads();

  const int jj = l16;                        // this lane's local hidden col
  const int gcr = col0 + jj;
  const int gcz = 512 + col0 + jj;
  const int gcn = 1024 + col0 + jj;
  const float cr = bx[gcr] + bh[gcr];
  const float cz = bx[gcz] + bh[gcz];
  const float bxn = bx[gcn];
  const float bhn = bh[gcn];

  const int cb = w * 16 + q * 4;             // C-layout batch base
  const int ab = w * 16 + l16;               // A-layout batch row

  const floatx4 fz = {0.f, 0.f, 0.f, 0.f};
  float h[4] = {0.f, 0.f, 0.f, 0.f};

  // x fragments for the NEXT step, held in registers.
  float4 fpre[XM ? 2 * NKS : 1];
  short8 bpre[XM ? 1 : NKS];

  auto load_x = [&](int t) {
    if (XM) {
      const float* p = xf + ((long)ab * 512 + t) * 512 + q * 8;
#pragma unroll
      for (int ks = 0; ks < NKS; ++ks) {
        fpre[2 * ks]     = *(const float4*)(p + ks * 32);
        fpre[2 * ks + 1] = *(const float4*)(p + ks * 32 + 4);
      }
    } else {
      const unsigned short* p = xb + ((long)t * 32 + ab) * 1024 + q * 8;
#pragma unroll
      for (int ks = 0; ks < NKS; ++ks)
        bpre[ks] = *(const short8*)(p + ks * 32);
    }
  };

  // gx from prefetched registers: pure VALU + LDS + MFMA (no memory latency)
  auto mfma_gx = [&](floatx4& gr, floatx4& gz, floatx4& gn) {
    gr = fz; gz = fz; gn = fz;
#pragma unroll
    for (int ks = 0; ks < NKS; ++ks) {
      short8 a = XM ? cvt8(fpre[2 * ks], fpre[2 * ks + 1]) : bpre[ks];
      short8 vr = *(const short8*)(wxs + (jj) * WXW + ks * 32 + q * 8);
      short8 vz = *(const short8*)(wxs + (16 + jj) * WXW + ks * 32 + q * 8);
      short8 vn = *(const short8*)(wxs + (32 + jj) * WXW + ks * 32 + q * 8);
      gr = __builtin_amdgcn_mfma_f32_16x16x32_bf16(a, vr, gr, 0, 0, 0);
      gz = __builtin_amdgcn_mfma_f32_16x16x32_bf16(a, vz, gz, 0, 0, 0);
      gn = __builtin_amdgcn_mfma_f32_16x16x32_bf16(a, vn, gn, 0, 0, 0);
    }
  };

  floatx4 gxr, gxz, gxn;
  { const int t0 = fw ? 0 : 511; load_x(t0); mfma_gx(gxr, gxz, gxn); }

  for (int it = 0; it < 512; ++it) {
    const int t = fw ? it : 511 - it;

    // issue h_prev atomic loads first, then next-x prefetch (independent)
    short8 af[16];
    if (it > 0) {
      const unsigned short* hbase;
      if (EM == 0) {
        const int tprev = fw ? t - 1 : t + 1;
        hbase = exch + ((long)tprev * 32 + ab) * 1024 + dirofs;
      } else {
        const int slot_r = (it + 1) & 1;     // slot written at it-1
        hbase = exch + ((long)slot_r * 32 + ab) * 1024 + dirofs;
      }
#pragma unroll
      for (int ks = 0; ks < 16; ++ks) {
        u64* p = (u64*)(hbase + ks * 32 + q * 8);
        union { u64 u[2]; short8 s; } t8;
        t8.u[0] = __hip_atomic_load(p,     __ATOMIC_RELAXED, __HIP_MEMORY_SCOPE_AGENT);
        t8.u[1] = __hip_atomic_load(p + 1, __ATOMIC_RELAXED, __HIP_MEMORY_SCOPE_AGENT);
        af[ks] = t8.s;
      }
    }
    if (it < 511) {
      const int tn2 = fw ? (it + 1) : (511 - (it + 1));
      load_x(tn2);   // in flight during gh MFMAs + gates
    }

    floatx4 ar = fz, az = fz, an = fz;
    if (it > 0) {
#pragma unroll
      for (int ks = 0; ks < 16; ++ks) {
        short8 vr = *(const short8*)(whs + (jj) * 520 + ks * 32 + q * 8);
        short8 vz = *(const short8*)(whs + (16 + jj) * 520 + ks * 32 + q * 8);
        short8 vn = *(const short8*)(whs + (32 + jj) * 520 + ks * 32 + q * 8);
        ar = __builtin_amdgcn_mfma_f32_16x16x32_bf16(af[ks], vr, ar, 0, 0, 0);
        az = __builtin_amdgcn_mfma_f32_16x16x32_bf16(af[ks], vz, az, 0, 0, 0);
        an = __builtin_amdgcn_mfma_f32_16x16x32_bf16(af[ks], vn, an, 0, 0, 0);
      }
    }

    unsigned short hb16[4];
#pragma unroll
    for (int r = 0; r < 4; ++r) {
      const float xr = sane(gxr[r] + ar[r] + cr, 60.f);
      const float xz = sane(gxz[r] + az[r] + cz, 60.f);
      const float rr = 1.f / (1.f + __expf(-xr));
      const float zz = 1.f / (1.f + __expf(-xz));
      const float xn = sane(gxn[r] + bxn + rr * (an[r] + bhn), 30.f);
      const float e2 = __expf(-2.f * xn);
      const float nn = (1.f - e2) / (1.f + e2);
      h[r] = (1.f - zz) * nn + zz * h[r];
      hb16[r] = f2bf(h[r]);
    }

    // exchange: pack 2 adjacent cols -> one 32-bit agent-scope atomic store
    unsigned int hw[4];
#pragma unroll
    for (int r = 0; r < 4; ++r) {
      int v = hb16[r];
      int p = __shfl_xor(v, 1);
      hw[r] = (unsigned int)(v & 0xffff) | ((unsigned int)(p & 0xffff) << 16);
    }
    if ((jj & 1) == 0) {
      const int colw = (dirofs + col0 + jj) >> 1;
#pragma unroll
      for (int r = 0; r < 4; ++r) {
        const long eidx = (EM == 0)
            ? (((long)t * 32 + cb + r) * 512 + colw)
            : (((long)(it & 1) * 32 + cb + r) * 512 + colw);
        __hip_atomic_store(exch32 + eidx, hw[r],
                           __ATOMIC_RELAXED, __HIP_MEMORY_SCOPE_AGENT);
      }
    }
    if (EM == 1) {   // float32 main output [B][S][1024]
#pragma unroll
      for (int r = 0; r < 4; ++r)
        omain[(long)(cb + r) * 524288 + (long)t * 1024 + dirofs + col0 + jj] = h[r];
    }

    if (it == 511) {
      float* oh = fw ? out_hf : out_hb;
#pragma unroll
      for (int r = 0; r < 4; ++r)
        oh[(cb + r) * 512 + col0 + jj] = h[r];
    } else {
      __syncthreads();   // vmcnt(0): h atomics acked at coherence point
      if (tid == 0)
        __hip_atomic_store(&flags[bid * 16], it + 1,
                           __ATOMIC_RELEASE, __HIP_MEMORY_SCOPE_AGENT);
      // spin-window compute: gx(t+1) from registers (no memory traffic)
      mfma_gx(gxr, gxz, gxn);
      // only wave0 lanes 0..31 poll; one padded flag line per peer
      if (tid < 32) {
        const int pf = ((fw ? 0 : 32) + tid) * 16;
        while (__hip_atomic_load(&flags[pf], __ATOMIC_RELAXED,
                                 __HIP_MEMORY_SCOPE_AGENT) < it + 1)
          __builtin_amdgcn_s_sleep(2);
      }
      __syncthreads();   // all threads' subsequent loads ordered after poll
    }
  }
}

// ---------------------------------------------------------------------------
// ws layout (total 33,693,696 B ~= 32.1 MiB):
//   y0    @ 0          : 33554432   bf16 [512][32][1024]
//   ring1 @ 33554432   : 131072     bf16 [2][32][1024]
//   flags @ 33685504   : 8192       2 layers x 64 flags x 64B padding
// d_out (float32): main [32][512][1024] @0, h_fw @16777216, h_bw @16809984.
// ---------------------------------------------------------------------------
extern "C" void kernel_launch(void* const* d_in, const int* in_sizes, int n_in,
                              void* d_out, int out_size, void* d_ws, size_t ws_size,
                              hipStream_t stream)
{
  (void)in_sizes; (void)n_in; (void)out_size; (void)ws_size;

  const float* x    = (const float*)d_in[0];
  const float* wxf0 = (const float*)d_in[1];
  const float* bxf0 = (const float*)d_in[2];
  const float* whf0 = (const float*)d_in[3];
  const float* bhf0 = (const float*)d_in[4];
  const float* wxb0 = (const float*)d_in[5];
  const float* bxb0 = (const float*)d_in[6];
  const float* whb0 = (const float*)d_in[7];
  const float* bhb0 = (const float*)d_in[8];
  const float* wxf1 = (const float*)d_in[9];
  const float* bxf1 = (const float*)d_in[10];
  const float* whf1 = (const float*)d_in[11];
  const float* bhf1 = (const float*)d_in[12];
  const float* wxb1 = (const float*)d_in[13];
  const float* bxb1 = (const float*)d_in[14];
  const float* whb1 = (const float*)d_in[15];
  const float* bhb1 = (const float*)d_in[16];

  char* ws = (char*)d_ws;
  unsigned short* y0    = (unsigned short*)(ws);
  unsigned short* ring1 = (unsigned short*)(ws + 33554432L);
  int* flags0           = (int*)(ws + 33685504L);
  int* flags1           = (int*)(ws + 33685504L + 4096L);

  float* out = (float*)d_out;
  float* out_hf0 = out + 16777216L;
  float* out_hf1 = out + 16777216L + 16384L;
  float* out_hb0 = out + 16777216L + 32768L;
  float* out_hb1 = out + 16777216L + 49152L;

  const size_t lds0 = (size_t)(48 * 520 + 48 * (512 + 8)) * 2;    //  99,840 B
  const size_t lds1 = (size_t)(48 * 520 + 48 * (1024 + 8)) * 2;   // 148,992 B
  (void)hipFuncSetAttribute((const void*)gru_layer<512, 1, 0>,
                            hipFuncAttributeMaxDynamicSharedMemorySize, (int)lds0);
  (void)hipFuncSetAttribute((const void*)gru_layer<1024, 0, 1>,
                            hipFuncAttributeMaxDynamicSharedMemorySize, (int)lds1);

  hipMemsetAsync(flags0, 0, 8192, stream);

  // layer 0: x float [B][S][512] -> y0 bf16 [S][B][1024] (+ h outputs)
  gru_layer<512, 1, 0><<<dim3(64), dim3(128), lds0, stream>>>(
      x, nullptr, wxf0, bxf0, whf0, bhf0, wxb0, bxb0, whb0, bhb0,
      y0, nullptr, out_hf0, out_hb0, flags0);

  // layer 1: y0 bf16 [S][B][1024] -> d_out main float [B][S][1024] (+ h)
  gru_layer<1024, 0, 1><<<dim3(64), dim3(128), lds1, stream>>>(
      nullptr, y0, wxf1, bxf1, whf1, bhf1, wxb1, bxb1, whb1, bhb1,
      ring1, out, out_hf1, out_hb1, flags1);
}